// Round 7
// baseline (106.047 us; speedup 1.0000x reference)
//
#include <hip/hip_runtime.h>
#include <hip/hip_bf16.h>
#include <math.h>

#define NPAIR 4096       // N = B*S
#define D 128
#define TWO_N 8192
#define NSLAB 64         // 16 jc-slabs x 4 waves, race-free partial rows
// Rb rows pre-scaled by ALPHA = sqrt(2*log2(e)): MFMA acc == 2*log2(e)*sim,
// so exp(2*sim) == exp2(acc) -> bare v_exp_f32 in the epilogue.
#define ALPHA 1.6986436f

typedef short bf16x8 __attribute__((ext_vector_type(8)));
typedef float f32x4 __attribute__((ext_vector_type(4)));

__device__ __forceinline__ void async_ld16(void* lds, const void* g) {
    // async global->LDS DMA, 16B/lane; LDS dest = wave-uniform base + lane*16
    __builtin_amdgcn_global_load_lds(
        (__attribute__((address_space(1))) const unsigned int*)g,
        (__attribute__((address_space(3))) unsigned int*)lds, 16, 0, 0);
}

__device__ inline unsigned short f2bf(float x) {
    union { float f; unsigned u; } v; v.f = x;
    unsigned u = v.u;
    unsigned r = u + 0x7fffu + ((u >> 16) & 1u);   // round-to-nearest-even
    return (unsigned short)(r >> 16);
}

// 1024 blocks x 256 threads; wave w handles pair-row k = blockIdx*4 + w.
// Emits ALPHA-scaled bf16 rows; pos[] stays exact fp32. Zero-inits out[0].
__global__ __launch_bounds__(256) void norm_kernel(const float* __restrict__ zi,
                                                   const float* __restrict__ zj,
                                                   unsigned int* __restrict__ Rb,
                                                   float* __restrict__ pos,
                                                   float* __restrict__ out) {
    if (blockIdx.x == 0 && threadIdx.x == 0) out[0] = 0.f;
    int k = blockIdx.x * 4 + (threadIdx.x >> 6);
    int t = threadIdx.x & 63;                 // 2 elems each
    const float2 a = *(const float2*)(zi + k * D + 2 * t);
    const float2 b = *(const float2*)(zj + k * D + 2 * t);
    float si = a.x * a.x + a.y * a.y;
    float sj = b.x * b.x + b.y * b.y;
    float dt = a.x * b.x + a.y * b.y;
    #pragma unroll
    for (int m = 1; m < 64; m <<= 1) {
        si += __shfl_xor(si, m, 64);
        sj += __shfl_xor(sj, m, 64);
        dt += __shfl_xor(dt, m, 64);
    }
    float ii = 1.0f / fmaxf(sqrtf(si), 1e-12f);
    float ij = 1.0f / fmaxf(sqrtf(sj), 1e-12f);
    if (t == 0) pos[k] = dt * ii * ij;        // exact (unscaled) positive sim
    ii *= ALPHA; ij *= ALPHA;
    unsigned short b0 = f2bf(a.x * ii), b1 = f2bf(a.y * ii);
    Rb[k * (D / 2) + t] = (unsigned)b0 | ((unsigned)b1 << 16);
    b0 = f2bf(b.x * ij); b1 = f2bf(b.y * ij);
    Rb[(k + NPAIR) * (D / 2) + t] = (unsigned)b0 | ((unsigned)b1 << 16);
}

// 2048 blocks: bi = b>>4 (64-row stripe), jc = b&15 (512-col slab, 8 jt-tiles
// of 64 cols). Small block -> 4-5 blocks/CU (16-20 waves) so barrier drains
// overlap across independent blocks. Wave = 64 rows x 16 cols: A fragments
// resident in regs; B tile (16KB) streams through a 2x16KB LDS double buffer
// via async global_load_lds (XOR-swizzled gather so ds_read_b128 fragment
// reads are conflict-free). 4 ds_read : 16 MFMA per jt per wave.
__global__ __launch_bounds__(256, 4) void simexp_kernel(const uint4* __restrict__ Rb,
                                                        float* __restrict__ rspart) {
    __shared__ uint4 Bs[2][1024];        // [buf][colrow*16 + piece]; 16KB each
    const int bi = blockIdx.x >> 4;      // 0..127
    const int jc = blockIdx.x & 15;      // 0..15
    const int tid = threadIdx.x;
    const int wave = tid >> 6, lane = tid & 63;
    const int rp = lane & 15, q = lane >> 4;

    // A fragments: row = bi*64 + rt*16 + rp, chunk = kt*4 + q
    bf16x8 afr[4][4];                    // [kt][rt]
    {
        const uint4* Ab = Rb + (bi * 64 + rp) * 16;
        #pragma unroll
        for (int kt = 0; kt < 4; ++kt)
            #pragma unroll
            for (int rt = 0; rt < 4; ++rt)
                afr[kt][rt] = *(const bf16x8*)&Ab[rt * 256 + kt * 4 + q];
    }

    // B staging: wave w stages local col-rows w*16..w*16+15 (4 issues x 4 rows).
    // Issue it, lane l: row_local = w*16 + it*4 + q', piece = rp ^ (it*4 + q')
    // where q'=(l>>4): global src per-lane, swizzled within the 256B row so the
    // contiguous LDS deposit yields conflict-free swizzled storage.
    const char* Rbb = (const char*)Rb;
    const char* gslab = Rbb + (size_t)(jc * 512) * 256;

    float rs[16];
    #pragma unroll
    for (int i = 0; i < 16; ++i) rs[i] = 0.f;

    // prefetch jt=0
    #pragma unroll
    for (int it = 0; it < 4; ++it) {
        int c4 = it * 4 + q;                         // row_local & 15
        const char* g = gslab + (wave * 16 + c4) * 256 + ((rp ^ c4) << 4);
        async_ld16((char*)&Bs[0][0] + wave * 4096 + it * 1024, g);
    }

    for (int jt = 0; jt < 8; ++jt) {
        const int cur = jt & 1;
        __syncthreads();                 // drains own prefetch of jt

        if (jt < 7) {                    // prefetch jt+1; in flight during compute
            #pragma unroll
            for (int it = 0; it < 4; ++it) {
                int c4 = it * 4 + q;
                const char* g = gslab + ((jt + 1) * 64 + wave * 16 + c4) * 256
                                + ((rp ^ c4) << 4);
                async_ld16((char*)&Bs[cur ^ 1][0] + wave * 4096 + it * 1024, g);
            }
        }

        // B fragments: col-row = wave*16 + rp, chunk kt*4+q stored at piece^rp
        bf16x8 bfr[4];
        #pragma unroll
        for (int kt = 0; kt < 4; ++kt)
            bfr[kt] = *(const bf16x8*)&Bs[cur][(wave * 16 + rp) * 16 + ((kt * 4 + q) ^ rp)];

        f32x4 acc[4] = {};
        #pragma unroll
        for (int kt = 0; kt < 4; ++kt)
            #pragma unroll
            for (int rt = 0; rt < 4; ++rt)
                acc[rt] = __builtin_amdgcn_mfma_f32_16x16x32_bf16(
                    afr[kt][rt], bfr[kt], acc[rt], 0, 0, 0);

        // D layout: col(jt-tile-local) = wave*16 + rp, row = rt*16 + q*4 + r
        if (jc * 512 + jt * 64 == bi * 64) {    // diagonal tile (block-uniform)
            #pragma unroll
            for (int rt = 0; rt < 4; ++rt)
                #pragma unroll
                for (int r = 0; r < 4; ++r) {
                    int ro = rt * 16 + q * 4 + r;
                    int co = wave * 16 + rp;
                    float e = exp2f(acc[rt][r]);
                    rs[rt * 4 + r] += (ro == co) ? 0.f : e;
                }
        } else {
            #pragma unroll
            for (int rt = 0; rt < 4; ++rt)
                #pragma unroll
                for (int r = 0; r < 4; ++r)
                    rs[rt * 4 + r] += exp2f(acc[rt][r]);
        }
    }

    // Reduce each reg across the 16 rp lanes; rp==0 stores its 16 rows.
    #pragma unroll
    for (int i = 0; i < 16; ++i) {
        float v = rs[i];
        v += __shfl_xor(v, 1, 64);
        v += __shfl_xor(v, 2, 64);
        v += __shfl_xor(v, 4, 64);
        v += __shfl_xor(v, 8, 64);
        rs[i] = v;
    }
    if (rp == 0) {
        const int slab = jc * 4 + wave;
        const int rowb = bi * 64 + q * 4;
        #pragma unroll
        for (int rt = 0; rt < 4; ++rt)
            #pragma unroll
            for (int r = 0; r < 4; ++r)
                rspart[slab * TWO_N + rowb + rt * 16 + r] = rs[rt * 4 + r];
    }
}

// 16 blocks x 256 threads; each thread does 2 rows; one atomicAdd per block.
__global__ __launch_bounds__(256) void finalize_kernel(const float* __restrict__ rspart,
                                                       const float* __restrict__ pos,
                                                       float* __restrict__ out) {
    __shared__ float red[4];
    int tid = threadIdx.x;
    float local = 0.f;
    #pragma unroll
    for (int i = 0; i < 2; ++i) {
        int k = blockIdx.x * 512 + i * 256 + tid;
        float rsum = 0.f;
        #pragma unroll
        for (int p = 0; p < NSLAB; ++p) rsum += rspart[p * TWO_N + k];
        float ps = pos[k & (NPAIR - 1)];
        float p2 = ps + ps;
        local += logf(rsum + __expf(p2)) - p2;
    }
    #pragma unroll
    for (int m = 1; m < 64; m <<= 1) local += __shfl_xor(local, m, 64);
    if ((tid & 63) == 0) red[tid >> 6] = local;
    __syncthreads();
    if (tid == 0) {
        float s = red[0] + red[1] + red[2] + red[3];
        atomicAdd(out, s * (1.0f / (float)TWO_N));
    }
}

extern "C" void kernel_launch(void* const* d_in, const int* in_sizes, int n_in,
                              void* d_out, int out_size, void* d_ws, size_t ws_size,
                              hipStream_t stream) {
    const float* zi = (const float*)d_in[0];
    const float* zj = (const float*)d_in[1];
    char* ws = (char*)d_ws;
    unsigned int* Rb = (unsigned int*)ws;                           // 2 MB bf16 rows
    float* rspart = (float*)(ws + 2 * 1024 * 1024);                 // 64*8192*4 = 2 MB
    float* pos = (float*)(ws + 4 * 1024 * 1024);                    // 16 KB

    norm_kernel<<<NPAIR / 4, 256, 0, stream>>>(zi, zj, Rb, pos, (float*)d_out);
    simexp_kernel<<<128 * 16, 256, 0, stream>>>((const uint4*)Rb, rspart);
    finalize_kernel<<<16, 256, 0, stream>>>(rspart, pos, (float*)d_out);
}

// Round 8
// 92.811 us; speedup vs baseline: 1.1426x; 1.1426x over previous
//
#include <hip/hip_runtime.h>
#include <hip/hip_bf16.h>
#include <math.h>

#define NPAIR 4096       // N = B*S
#define D 128
#define TWO_N 8192
#define NSLAB 32         // 8 jc-slabs x 4 waves, race-free partial rows
// Rb rows pre-scaled by ALPHA = sqrt(2*log2(e)): MFMA acc == 2*log2(e)*sim,
// so exp(2*sim) == exp2(acc) -> bare v_exp_f32 in the epilogue.
#define ALPHA 1.6986436f

typedef short bf16x8 __attribute__((ext_vector_type(8)));
typedef float f32x4 __attribute__((ext_vector_type(4)));

__device__ __forceinline__ void async_ld16(void* lds, const void* g) {
    // async global->LDS DMA, 16B/lane; LDS dest = wave-uniform base + lane*16
    __builtin_amdgcn_global_load_lds(
        (__attribute__((address_space(1))) const unsigned int*)g,
        (__attribute__((address_space(3))) unsigned int*)lds, 16, 0, 0);
}

__device__ inline unsigned short f2bf(float x) {
    union { float f; unsigned u; } v; v.f = x;
    unsigned u = v.u;
    unsigned r = u + 0x7fffu + ((u >> 16) & 1u);   // round-to-nearest-even
    return (unsigned short)(r >> 16);
}

// 1024 blocks x 256 threads; wave w handles pair-row k = blockIdx*4 + w.
// Emits ALPHA-scaled bf16 rows; pos[] stays exact fp32. Zero-inits out[0].
__global__ __launch_bounds__(256) void norm_kernel(const float* __restrict__ zi,
                                                   const float* __restrict__ zj,
                                                   unsigned int* __restrict__ Rb,
                                                   float* __restrict__ pos,
                                                   float* __restrict__ out) {
    if (blockIdx.x == 0 && threadIdx.x == 0) out[0] = 0.f;
    int k = blockIdx.x * 4 + (threadIdx.x >> 6);
    int t = threadIdx.x & 63;                 // 2 elems each
    const float2 a = *(const float2*)(zi + k * D + 2 * t);
    const float2 b = *(const float2*)(zj + k * D + 2 * t);
    float si = a.x * a.x + a.y * a.y;
    float sj = b.x * b.x + b.y * b.y;
    float dt = a.x * b.x + a.y * b.y;
    #pragma unroll
    for (int m = 1; m < 64; m <<= 1) {
        si += __shfl_xor(si, m, 64);
        sj += __shfl_xor(sj, m, 64);
        dt += __shfl_xor(dt, m, 64);
    }
    float ii = 1.0f / fmaxf(sqrtf(si), 1e-12f);
    float ij = 1.0f / fmaxf(sqrtf(sj), 1e-12f);
    if (t == 0) pos[k] = dt * ii * ij;        // exact (unscaled) positive sim
    ii *= ALPHA; ij *= ALPHA;
    unsigned short b0 = f2bf(a.x * ii), b1 = f2bf(a.y * ii);
    Rb[k * (D / 2) + t] = (unsigned)b0 | ((unsigned)b1 << 16);
    b0 = f2bf(b.x * ij); b1 = f2bf(b.y * ij);
    Rb[(k + NPAIR) * (D / 2) + t] = (unsigned)b0 | ((unsigned)b1 << 16);
}

// 1024 blocks: bi = b>>3 (64-row stripe), jc = b&7 (1024-col slab, 16 jt
// tiles of 64 cols). ZERO BARRIERS: each wave owns a private 16-col panel,
// DMAs it into its own LDS double-buffer (async global_load_lds), and is the
// only reader -> the only sync needed is the wave's own vmcnt wait at loop
// top (covers the prefetch issued one full compute phase earlier). A
// fragments register-resident; XOR-swizzled panel so ds_read_b128 fragment
// reads are conflict-free (R6-verified pattern). 4 ds_read : 16 MFMA per jt.
__global__ __launch_bounds__(256, 3) void simexp_kernel(const uint4* __restrict__ Rb,
                                                        float* __restrict__ rspart) {
    __shared__ uint4 Bs[4][2][256];      // [wave][buf][16 colrows x 16 pieces]
    const int bi = blockIdx.x >> 3;      // 0..127 (64-row stripe)
    const int jc = blockIdx.x & 7;       // 0..7  (1024-col slab)
    const int tid = threadIdx.x;
    const int wave = tid >> 6, lane = tid & 63;
    const int rp = lane & 15, q = lane >> 4;

    // A fragments: row = bi*64 + rt*16 + rp, chunk = kt*4 + q
    bf16x8 afr[4][4];                    // [kt][rt]
    {
        const uint4* Ab = Rb + (bi * 64 + rp) * 16;
        #pragma unroll
        for (int kt = 0; kt < 4; ++kt)
            #pragma unroll
            for (int rt = 0; rt < 4; ++rt)
                afr[kt][rt] = *(const bf16x8*)&Ab[rt * 256 + kt * 4 + q];
    }

    // Wave-private B panel: cols jc*1024 + jt*64 + wave*16 + [0,16).
    // DMA issue it (0..3), this lane: colrow_local = it*4 + q,
    // src byte = (grow)*256 + ((rp ^ colrow_local)<<4); LDS deposit is
    // contiguous (base + it*1024 + lane*16) -> swizzled storage.
    const char* Rbb = (const char*)Rb;
    const char* gpanel = Rbb + (size_t)(jc * 1024 + wave * 16) * 256;
    char* lpanel = (char*)&Bs[wave][0][0];
    const int c4 = q;                    // it*4 + q computed per issue below

    float rs[16];
    #pragma unroll
    for (int i = 0; i < 16; ++i) rs[i] = 0.f;

    // prefetch jt=0 into buf 0
    #pragma unroll
    for (int it = 0; it < 4; ++it) {
        int cr = it * 4 + c4;
        async_ld16(lpanel + it * 1024,
                   gpanel + cr * 256 + ((rp ^ cr) << 4));
    }

    const int diagbase = bi * 64 - jc * 1024;   // diag col offset in slab

    #pragma unroll
    for (int jt = 0; jt < 16; ++jt) {
        const int cur = jt & 1;
        // wait for own outstanding DMA (prefetch of this jt's buffer)
        __builtin_amdgcn_s_waitcnt(0x0F70);     // vmcnt(0) only

        // B fragments first (so prefetch below doesn't need finer vmcnt)
        bf16x8 bfr[4];
        #pragma unroll
        for (int kt = 0; kt < 4; ++kt)
            bfr[kt] = *(const bf16x8*)&Bs[wave][cur][rp * 16 + ((kt * 4 + q) ^ rp)];

        if (jt < 15) {                   // prefetch jt+1 into the other buffer
            #pragma unroll
            for (int it = 0; it < 4; ++it) {
                int cr = it * 4 + c4;
                async_ld16(lpanel + (cur ^ 1) * 4096 + it * 1024,
                           gpanel + ((jt + 1) * 64 + cr) * 256 + ((rp ^ cr) << 4));
            }
        }

        f32x4 acc[4] = {};
        #pragma unroll
        for (int kt = 0; kt < 4; ++kt)
            #pragma unroll
            for (int rt = 0; rt < 4; ++rt)
                acc[rt] = __builtin_amdgcn_mfma_f32_16x16x32_bf16(
                    afr[kt][rt], bfr[kt], acc[rt], 0, 0, 0);

        // D layout: col(tile-local) = wave*16 + rp, row = rt*16 + q*4 + r
        if (jt * 64 == diagbase) {       // the one jt tile holding the diagonal
            #pragma unroll
            for (int rt = 0; rt < 4; ++rt)
                #pragma unroll
                for (int r = 0; r < 4; ++r) {
                    int ro = rt * 16 + q * 4 + r;
                    int co = wave * 16 + rp;
                    float e = exp2f(acc[rt][r]);
                    rs[rt * 4 + r] += (ro == co) ? 0.f : e;
                }
        } else {
            #pragma unroll
            for (int rt = 0; rt < 4; ++rt)
                #pragma unroll
                for (int r = 0; r < 4; ++r)
                    rs[rt * 4 + r] += exp2f(acc[rt][r]);
        }
    }

    // Reduce each reg across the 16 rp lanes; rp==0 stores its 16 rows.
    #pragma unroll
    for (int i = 0; i < 16; ++i) {
        float v = rs[i];
        v += __shfl_xor(v, 1, 64);
        v += __shfl_xor(v, 2, 64);
        v += __shfl_xor(v, 4, 64);
        v += __shfl_xor(v, 8, 64);
        rs[i] = v;
    }
    if (rp == 0) {
        const int slab = jc * 4 + wave;
        const int rowb = bi * 64 + q * 4;
        #pragma unroll
        for (int rt = 0; rt < 4; ++rt)
            #pragma unroll
            for (int r = 0; r < 4; ++r)
                rspart[slab * TWO_N + rowb + rt * 16 + r] = rs[rt * 4 + r];
    }
}

// 16 blocks x 256 threads; each thread does 2 rows; one atomicAdd per block.
__global__ __launch_bounds__(256) void finalize_kernel(const float* __restrict__ rspart,
                                                       const float* __restrict__ pos,
                                                       float* __restrict__ out) {
    __shared__ float red[4];
    int tid = threadIdx.x;
    float local = 0.f;
    #pragma unroll
    for (int i = 0; i < 2; ++i) {
        int k = blockIdx.x * 512 + i * 256 + tid;
        float rsum = 0.f;
        #pragma unroll
        for (int p = 0; p < NSLAB; ++p) rsum += rspart[p * TWO_N + k];
        float ps = pos[k & (NPAIR - 1)];
        float p2 = ps + ps;
        local += logf(rsum + __expf(p2)) - p2;
    }
    #pragma unroll
    for (int m = 1; m < 64; m <<= 1) local += __shfl_xor(local, m, 64);
    if ((tid & 63) == 0) red[tid >> 6] = local;
    __syncthreads();
    if (tid == 0) {
        float s = red[0] + red[1] + red[2] + red[3];
        atomicAdd(out, s * (1.0f / (float)TWO_N));
    }
}

extern "C" void kernel_launch(void* const* d_in, const int* in_sizes, int n_in,
                              void* d_out, int out_size, void* d_ws, size_t ws_size,
                              hipStream_t stream) {
    const float* zi = (const float*)d_in[0];
    const float* zj = (const float*)d_in[1];
    char* ws = (char*)d_ws;
    unsigned int* Rb = (unsigned int*)ws;                           // 2 MB bf16 rows
    float* rspart = (float*)(ws + 2 * 1024 * 1024);                 // 32*8192*4 = 1 MB
    float* pos = (float*)(ws + 3 * 1024 * 1024);                    // 16 KB

    norm_kernel<<<NPAIR / 4, 256, 0, stream>>>(zi, zj, Rb, pos, (float*)d_out);
    simexp_kernel<<<128 * 8, 256, 0, stream>>>((const uint4*)Rb, rspart);
    finalize_kernel<<<16, 256, 0, stream>>>(rspart, pos, (float*)d_out);
}

// Round 9
// 85.102 us; speedup vs baseline: 1.2461x; 1.0906x over previous
//
#include <hip/hip_runtime.h>
#include <hip/hip_bf16.h>
#include <math.h>

#define NPAIR 4096       // N = B*S
#define D 128
#define TWO_N 8192
#define NSLAB 32         // 8 jc-slabs x 4 waves, race-free partial rows
// Rb rows pre-scaled by ALPHA = sqrt(2*log2(e)): MFMA acc == 2*log2(e)*sim,
// so exp(2*sim) == exp2(acc) -> a single raw v_exp_f32 in the epilogue.
#define ALPHA 1.6986436f

typedef short bf16x8 __attribute__((ext_vector_type(8)));
typedef float f32x4 __attribute__((ext_vector_type(4)));

__device__ __forceinline__ void async_ld16(void* lds, const void* g) {
    // async global->LDS DMA, 16B/lane; LDS dest = wave-uniform base + lane*16
    __builtin_amdgcn_global_load_lds(
        (__attribute__((address_space(1))) const unsigned int*)g,
        (__attribute__((address_space(3))) unsigned int*)lds, 16, 0, 0);
}

__device__ inline unsigned short f2bf(float x) {
    union { float f; unsigned u; } v; v.f = x;
    unsigned u = v.u;
    unsigned r = u + 0x7fffu + ((u >> 16) & 1u);   // round-to-nearest-even
    return (unsigned short)(r >> 16);
}

// 1024 blocks x 256 threads; wave w handles pair-row k = blockIdx*4 + w.
// Emits ALPHA-scaled bf16 rows; pos[] stays exact fp32. Zero-inits out[0].
__global__ __launch_bounds__(256) void norm_kernel(const float* __restrict__ zi,
                                                   const float* __restrict__ zj,
                                                   unsigned int* __restrict__ Rb,
                                                   float* __restrict__ pos,
                                                   float* __restrict__ out) {
    if (blockIdx.x == 0 && threadIdx.x == 0) out[0] = 0.f;
    int k = blockIdx.x * 4 + (threadIdx.x >> 6);
    int t = threadIdx.x & 63;                 // 2 elems each
    const float2 a = *(const float2*)(zi + k * D + 2 * t);
    const float2 b = *(const float2*)(zj + k * D + 2 * t);
    float si = a.x * a.x + a.y * a.y;
    float sj = b.x * b.x + b.y * b.y;
    float dt = a.x * b.x + a.y * b.y;
    #pragma unroll
    for (int m = 1; m < 64; m <<= 1) {
        si += __shfl_xor(si, m, 64);
        sj += __shfl_xor(sj, m, 64);
        dt += __shfl_xor(dt, m, 64);
    }
    float ii = 1.0f / fmaxf(sqrtf(si), 1e-12f);
    float ij = 1.0f / fmaxf(sqrtf(sj), 1e-12f);
    if (t == 0) pos[k] = dt * ii * ij;        // exact (unscaled) positive sim
    ii *= ALPHA; ij *= ALPHA;
    unsigned short b0 = f2bf(a.x * ii), b1 = f2bf(a.y * ii);
    Rb[k * (D / 2) + t] = (unsigned)b0 | ((unsigned)b1 << 16);
    b0 = f2bf(b.x * ij); b1 = f2bf(b.y * ij);
    Rb[(k + NPAIR) * (D / 2) + t] = (unsigned)b0 | ((unsigned)b1 << 16);
}

// 1024 blocks: bi = b>>3 (64-row stripe), jc = b&7 (1024-col slab, 16 jt
// tiles of 64 cols). ZERO BARRIERS: each wave owns a private 16-col panel
// streamed through a wave-private TRIPLE buffer via async global_load_lds,
// prefetched TWO jt ahead; loop-top wait is vmcnt(4) (oldest prefetch only,
// next stays in flight -- AITER-style, possible only without barriers).
// Raw v_exp_f32 epilogue (libm exp2f was costing ~4x the VALU, R6 counters).
// XOR-swizzled panels: ds_read_b128 fragment reads are conflict-free.
__global__ __launch_bounds__(256, 3) void simexp_kernel(const uint4* __restrict__ Rb,
                                                        float* __restrict__ rspart) {
    __shared__ uint4 Bs[4][3][256];      // [wave][buf][16 colrows x 16 pieces]
    const int bi = blockIdx.x >> 3;      // 0..127 (64-row stripe)
    const int jc = blockIdx.x & 7;       // 0..7  (1024-col slab)
    const int tid = threadIdx.x;
    const int wave = tid >> 6, lane = tid & 63;
    const int rp = lane & 15, q = lane >> 4;

    // A fragments: row = bi*64 + rt*16 + rp, chunk = kt*4 + q
    bf16x8 afr[4][4];                    // [kt][rt]
    {
        const uint4* Ab = Rb + (bi * 64 + rp) * 16;
        #pragma unroll
        for (int kt = 0; kt < 4; ++kt)
            #pragma unroll
            for (int rt = 0; rt < 4; ++rt)
                afr[kt][rt] = *(const bf16x8*)&Ab[rt * 256 + kt * 4 + q];
    }

    // Wave-private B panel: cols jc*1024 + jt*64 + wave*16 + [0,16).
    // DMA issue it (0..3), this lane: colrow cr = it*4 + q,
    // src byte = cr*256 + ((rp^cr)<<4); contiguous LDS deposit -> LDS holds
    // (cr,piece) at uint4 index cr*16 + (piece^cr)  [R6/R7-verified swizzle].
    const char* Rbb = (const char*)Rb;
    const char* gpanel = Rbb + (size_t)(jc * 1024 + wave * 16) * 256;
    char* lpanel = (char*)&Bs[wave][0][0];

    float rs[16];
    #pragma unroll
    for (int i = 0; i < 16; ++i) rs[i] = 0.f;

    // prefetch jt=0 (buf 0) and jt=1 (buf 1): 8 DMAs outstanding
    #pragma unroll
    for (int j = 0; j < 2; ++j)
        #pragma unroll
        for (int it = 0; it < 4; ++it) {
            int cr = it * 4 + q;
            async_ld16(lpanel + j * 4096 + it * 1024,
                       gpanel + (j * 64 + cr) * 256 + ((rp ^ cr) << 4));
        }

    const int diagbase = bi * 64 - jc * 1024;   // diag col offset in slab

    #pragma unroll
    for (int jt = 0; jt < 16; ++jt) {
        // Wait for the OLDEST prefetch only (this jt's buffer); the jt+1
        // prefetch stays in flight. Tail iterations have fewer outstanding.
        if (jt < 14) __builtin_amdgcn_s_waitcnt(0x0F74);   // vmcnt(4)
        else         __builtin_amdgcn_s_waitcnt(0x0F70);   // vmcnt(0)

        const int cur = jt % 3;
        bf16x8 bfr[4];
        #pragma unroll
        for (int kt = 0; kt < 4; ++kt)
            bfr[kt] = *(const bf16x8*)&Bs[wave][cur][rp * 16 + ((kt * 4 + q) ^ rp)];

        if (jt < 14) {                   // prefetch jt+2 into buf (jt+2)%3
            const int nb = (jt + 2) % 3;
            #pragma unroll
            for (int it = 0; it < 4; ++it) {
                int cr = it * 4 + q;
                async_ld16(lpanel + nb * 4096 + it * 1024,
                           gpanel + ((jt + 2) * 64 + cr) * 256 + ((rp ^ cr) << 4));
            }
        }

        f32x4 acc[4] = {};
        #pragma unroll
        for (int kt = 0; kt < 4; ++kt)
            #pragma unroll
            for (int rt = 0; rt < 4; ++rt)
                acc[rt] = __builtin_amdgcn_mfma_f32_16x16x32_bf16(
                    afr[kt][rt], bfr[kt], acc[rt], 0, 0, 0);

        // D layout: col(tile-local) = wave*16 + rp, row = rt*16 + q*4 + r
        if (jt * 64 == diagbase) {       // the one jt tile holding the diagonal
            #pragma unroll
            for (int rt = 0; rt < 4; ++rt)
                #pragma unroll
                for (int r = 0; r < 4; ++r) {
                    int ro = rt * 16 + q * 4 + r;
                    int co = wave * 16 + rp;
                    float e = __builtin_amdgcn_exp2f(acc[rt][r]);
                    rs[rt * 4 + r] += (ro == co) ? 0.f : e;
                }
        } else {
            #pragma unroll
            for (int rt = 0; rt < 4; ++rt)
                #pragma unroll
                for (int r = 0; r < 4; ++r)
                    rs[rt * 4 + r] += __builtin_amdgcn_exp2f(acc[rt][r]);
        }
    }

    // Reduce each reg across the 16 rp lanes; rp==0 stores its 16 rows.
    #pragma unroll
    for (int i = 0; i < 16; ++i) {
        float v = rs[i];
        v += __shfl_xor(v, 1, 64);
        v += __shfl_xor(v, 2, 64);
        v += __shfl_xor(v, 4, 64);
        v += __shfl_xor(v, 8, 64);
        rs[i] = v;
    }
    if (rp == 0) {
        const int slab = jc * 4 + wave;
        const int rowb = bi * 64 + q * 4;
        #pragma unroll
        for (int rt = 0; rt < 4; ++rt)
            #pragma unroll
            for (int r = 0; r < 4; ++r)
                rspart[slab * TWO_N + rowb + rt * 16 + r] = rs[rt * 4 + r];
    }
}

// 16 blocks x 256 threads; each thread does 2 rows; one atomicAdd per block.
__global__ __launch_bounds__(256) void finalize_kernel(const float* __restrict__ rspart,
                                                       const float* __restrict__ pos,
                                                       float* __restrict__ out) {
    __shared__ float red[4];
    int tid = threadIdx.x;
    float local = 0.f;
    #pragma unroll
    for (int i = 0; i < 2; ++i) {
        int k = blockIdx.x * 512 + i * 256 + tid;
        float rsum = 0.f;
        #pragma unroll
        for (int p = 0; p < NSLAB; ++p) rsum += rspart[p * TWO_N + k];
        float ps = pos[k & (NPAIR - 1)];
        float p2 = ps + ps;
        local += logf(rsum + __expf(p2)) - p2;
    }
    #pragma unroll
    for (int m = 1; m < 64; m <<= 1) local += __shfl_xor(local, m, 64);
    if ((tid & 63) == 0) red[tid >> 6] = local;
    __syncthreads();
    if (tid == 0) {
        float s = red[0] + red[1] + red[2] + red[3];
        atomicAdd(out, s * (1.0f / (float)TWO_N));
    }
}

extern "C" void kernel_launch(void* const* d_in, const int* in_sizes, int n_in,
                              void* d_out, int out_size, void* d_ws, size_t ws_size,
                              hipStream_t stream) {
    const float* zi = (const float*)d_in[0];
    const float* zj = (const float*)d_in[1];
    char* ws = (char*)d_ws;
    unsigned int* Rb = (unsigned int*)ws;                           // 2 MB bf16 rows
    float* rspart = (float*)(ws + 2 * 1024 * 1024);                 // 32*8192*4 = 1 MB
    float* pos = (float*)(ws + 3 * 1024 * 1024);                    // 16 KB

    norm_kernel<<<NPAIR / 4, 256, 0, stream>>>(zi, zj, Rb, pos, (float*)d_out);
    simexp_kernel<<<128 * 8, 256, 0, stream>>>((const uint4*)Rb, rspart);
    finalize_kernel<<<16, 256, 0, stream>>>(rspart, pos, (float*)d_out);
}

// Round 10
// 78.958 us; speedup vs baseline: 1.3431x; 1.0778x over previous
//
#include <hip/hip_runtime.h>
#include <hip/hip_bf16.h>
#include <math.h>

#define NPAIR 4096       // N = B*S
#define D 128
#define TWO_N 8192
#define NSLAB 32         // 8 jc-slabs x 4 waves, race-free partial rows
// Rb rows pre-scaled by ALPHA = sqrt(2*log2(e)): MFMA acc == 2*log2(e)*sim,
// so exp(2*sim) == exp2(acc) -> a single raw v_exp_f32 in the epilogue.
#define ALPHA 1.6986436f

typedef float f32x4 __attribute__((ext_vector_type(4)));
typedef long lx2 __attribute__((ext_vector_type(2)));

__device__ __forceinline__ void async_ld16(void* lds, const void* g) {
    // async global->LDS DMA, 16B/lane; LDS dest = wave-uniform base + lane*16
    __builtin_amdgcn_global_load_lds(
        (__attribute__((address_space(1))) const unsigned int*)g,
        (__attribute__((address_space(3))) unsigned int*)lds, 16, 0, 0);
}

// 1024 blocks x 256 threads; wave w handles pair-row k = blockIdx*4 + w.
// Emits ALPHA-scaled fp8 e4m3 rows in q-grouped layout: chunk c (global k
// [c*8,c*8+8)) stored at byte (c&3)*32 + (c>>2)*8 -> each MFMA lane's 4
// K-chunks are 32 contiguous bytes. pos[] stays exact fp32.
__global__ __launch_bounds__(256) void norm_kernel(const float* __restrict__ zi,
                                                   const float* __restrict__ zj,
                                                   unsigned char* __restrict__ Rb,
                                                   float* __restrict__ pos,
                                                   float* __restrict__ out) {
    if (blockIdx.x == 0 && threadIdx.x == 0) out[0] = 0.f;
    int k = blockIdx.x * 4 + (threadIdx.x >> 6);
    int t = threadIdx.x & 63;                 // 2 elems each
    const float2 a = *(const float2*)(zi + k * D + 2 * t);
    const float2 b = *(const float2*)(zj + k * D + 2 * t);
    float si = a.x * a.x + a.y * a.y;
    float sj = b.x * b.x + b.y * b.y;
    float dt = a.x * b.x + a.y * b.y;
    #pragma unroll
    for (int m = 1; m < 64; m <<= 1) {
        si += __shfl_xor(si, m, 64);
        sj += __shfl_xor(sj, m, 64);
        dt += __shfl_xor(dt, m, 64);
    }
    float ii = 1.0f / fmaxf(sqrtf(si), 1e-12f);
    float ij = 1.0f / fmaxf(sqrtf(sj), 1e-12f);
    if (t == 0) pos[k] = dt * ii * ij;        // exact (unscaled) positive sim
    ii *= ALPHA; ij *= ALPHA;
    // elems e=2t,2t+1: chunk c = t>>2, byte = (c&3)*32 + (c>>2)*8 + 2*(t&3)
    int c = t >> 2;
    int posb = (c & 3) * 32 + (c >> 2) * 8 + 2 * (t & 3);
    int r0 = __builtin_amdgcn_cvt_pk_fp8_f32(a.x * ii, a.y * ii, 0, false);
    *(unsigned short*)(Rb + (size_t)k * 128 + posb) = (unsigned short)r0;
    int r1 = __builtin_amdgcn_cvt_pk_fp8_f32(b.x * ij, b.y * ij, 0, false);
    *(unsigned short*)(Rb + (size_t)(k + NPAIR) * 128 + posb) = (unsigned short)r1;
}

// 1024 blocks: bi = b>>3 (64-row stripe), jc = b&7 (1024-col slab, 16 jt
// tiles of 64 cols). fp8 e4m3 MFMA (bf16 rate, half the bytes). ZERO
// BARRIERS: wave-private 16-col panels (2KB) stream through a TRIPLE buffer
// (24KB/block -> 4 blocks/CU, grid = ONE fully-resident round, no tail),
// prefetched two jt ahead; loop-top wait = vmcnt(2) (oldest panel only).
// Piece-XOR swizzle (p ^ (col&7)) -> ds_read_b128 2-way (free) conflicts.
__global__ __launch_bounds__(256, 4) void simexp_kernel(const unsigned char* __restrict__ Rb,
                                                        float* __restrict__ rspart) {
    __shared__ uint4 Bs[4][3][128];      // [wave][buf][16 cols x 8 pieces] 2KB/buf
    const int bi = blockIdx.x >> 3;      // 0..127 (64-row stripe)
    const int jc = blockIdx.x & 7;       // 0..7  (1024-col slab)
    const int tid = threadIdx.x;
    const int wave = tid >> 6, lane = tid & 63;
    const int rp = lane & 15, q = lane >> 4;

    // A fragments: row = bi*64 + rt*16 + rp; lane's 4 K-chunks = 32B at q*32.
    long afr[4][4];                      // [kt][rt]
    {
        const unsigned char* Ab = Rb + (size_t)(bi * 64 + rp) * 128 + q * 32;
        #pragma unroll
        for (int rt = 0; rt < 4; ++rt) {
            lx2 h0 = *(const lx2*)(Ab + rt * 16 * 128);
            lx2 h1 = *(const lx2*)(Ab + rt * 16 * 128 + 16);
            afr[0][rt] = h0.x;  afr[1][rt] = h0.y;
            afr[2][rt] = h1.x;  afr[3][rt] = h1.y;
        }
    }

    // Wave-private B panel: cols jc*1024 + jt*64 + wave*16 + [0,16), 128B/col,
    // 2 DMAs/jt (8 cols each). DMA d, lane l: col cr = d*8 + (l>>3), stored
    // piece p' = l&7, global piece p = p' ^ (cr&7)  [slot = cr*8 + (p^(cr&7))].
    const unsigned char* gslab = Rb + (size_t)(jc * 1024 + wave * 16) * 128;
    char* lpanel = (char*)&Bs[wave][0][0];
    const int laneoff = (lane >> 3) * 128 + (((lane & 7) ^ ((lane >> 3) & 7)) << 4);

    float rs[16];
    #pragma unroll
    for (int i = 0; i < 16; ++i) rs[i] = 0.f;

    // prefetch jt=0 (buf0) and jt=1 (buf1): 4 DMAs outstanding
    #pragma unroll
    for (int j = 0; j < 2; ++j)
        #pragma unroll
        for (int d = 0; d < 2; ++d)
            async_ld16(lpanel + j * 2048 + d * 1024,
                       gslab + j * 8192 + d * 1024 + laneoff);

    const int diagbase = bi * 64 - jc * 1024;   // diag col offset in slab
    const int slot0 = rp * 8;
    const int sw = rp & 7;

    #pragma unroll
    for (int jt = 0; jt < 16; ++jt) {
        // Wait only for the OLDEST panel (this jt's 2 DMAs); next stays in flight.
        if (jt < 14) __builtin_amdgcn_s_waitcnt(0x0F72);   // vmcnt(2)
        else         __builtin_amdgcn_s_waitcnt(0x0F70);   // vmcnt(0)

        const int cur = jt % 3;
        const uint4* P = &Bs[wave][cur][0];
        lx2 v0 = *(const lx2*)&P[slot0 + ((q * 2 + 0) ^ sw)];  // kt0, kt1
        lx2 v1 = *(const lx2*)&P[slot0 + ((q * 2 + 1) ^ sw)];  // kt2, kt3

        if (jt < 14) {                   // prefetch jt+2 into buf (jt+2)%3
            const int nb = (jt + 2) % 3;
            #pragma unroll
            for (int d = 0; d < 2; ++d)
                async_ld16(lpanel + nb * 2048 + d * 1024,
                           gslab + (jt + 2) * 8192 + d * 1024 + laneoff);
        }

        f32x4 acc[4] = {};
        #pragma unroll
        for (int rt = 0; rt < 4; ++rt) {
            acc[rt] = __builtin_amdgcn_mfma_f32_16x16x32_fp8_fp8(afr[0][rt], v0.x, acc[rt], 0, 0, 0);
            acc[rt] = __builtin_amdgcn_mfma_f32_16x16x32_fp8_fp8(afr[1][rt], v0.y, acc[rt], 0, 0, 0);
            acc[rt] = __builtin_amdgcn_mfma_f32_16x16x32_fp8_fp8(afr[2][rt], v1.x, acc[rt], 0, 0, 0);
            acc[rt] = __builtin_amdgcn_mfma_f32_16x16x32_fp8_fp8(afr[3][rt], v1.y, acc[rt], 0, 0, 0);
        }

        // D layout: col(tile-local) = wave*16 + rp, row = rt*16 + q*4 + r
        if (jt * 64 == diagbase) {       // the one jt tile holding the diagonal
            #pragma unroll
            for (int rt = 0; rt < 4; ++rt)
                #pragma unroll
                for (int r = 0; r < 4; ++r) {
                    int ro = rt * 16 + q * 4 + r;
                    int co = wave * 16 + rp;
                    float e = __builtin_amdgcn_exp2f(acc[rt][r]);
                    rs[rt * 4 + r] += (ro == co) ? 0.f : e;
                }
        } else {
            #pragma unroll
            for (int rt = 0; rt < 4; ++rt)
                #pragma unroll
                for (int r = 0; r < 4; ++r)
                    rs[rt * 4 + r] += __builtin_amdgcn_exp2f(acc[rt][r]);
        }
    }

    // Reduce each reg across the 16 rp lanes; rp==0 stores its 16 rows.
    #pragma unroll
    for (int i = 0; i < 16; ++i) {
        float v = rs[i];
        v += __shfl_xor(v, 1, 64);
        v += __shfl_xor(v, 2, 64);
        v += __shfl_xor(v, 4, 64);
        v += __shfl_xor(v, 8, 64);
        rs[i] = v;
    }
    if (rp == 0) {
        const int slab = jc * 4 + wave;
        const int rowb = bi * 64 + q * 4;
        #pragma unroll
        for (int rt = 0; rt < 4; ++rt)
            #pragma unroll
            for (int r = 0; r < 4; ++r)
                rspart[slab * TWO_N + rowb + rt * 16 + r] = rs[rt * 4 + r];
    }
}

// 16 blocks x 256 threads; each thread does 2 rows; one atomicAdd per block.
__global__ __launch_bounds__(256) void finalize_kernel(const float* __restrict__ rspart,
                                                       const float* __restrict__ pos,
                                                       float* __restrict__ out) {
    __shared__ float red[4];
    int tid = threadIdx.x;
    float local = 0.f;
    #pragma unroll
    for (int i = 0; i < 2; ++i) {
        int k = blockIdx.x * 512 + i * 256 + tid;
        float rsum = 0.f;
        #pragma unroll
        for (int p = 0; p < NSLAB; ++p) rsum += rspart[p * TWO_N + k];
        float ps = pos[k & (NPAIR - 1)];
        float p2 = ps + ps;
        local += logf(rsum + __expf(p2)) - p2;
    }
    #pragma unroll
    for (int m = 1; m < 64; m <<= 1) local += __shfl_xor(local, m, 64);
    if ((tid & 63) == 0) red[tid >> 6] = local;
    __syncthreads();
    if (tid == 0) {
        float s = red[0] + red[1] + red[2] + red[3];
        atomicAdd(out, s * (1.0f / (float)TWO_N));
    }
}

extern "C" void kernel_launch(void* const* d_in, const int* in_sizes, int n_in,
                              void* d_out, int out_size, void* d_ws, size_t ws_size,
                              hipStream_t stream) {
    const float* zi = (const float*)d_in[0];
    const float* zj = (const float*)d_in[1];
    char* ws = (char*)d_ws;
    unsigned char* Rb = (unsigned char*)ws;                         // 1 MB fp8 rows
    float* rspart = (float*)(ws + 1 * 1024 * 1024);                 // 32*8192*4 = 1 MB
    float* pos = (float*)(ws + 2 * 1024 * 1024);                    // 16 KB

    norm_kernel<<<NPAIR / 4, 256, 0, stream>>>(zi, zj, Rb, pos, (float*)d_out);
    simexp_kernel<<<128 * 8, 256, 0, stream>>>(Rb, rspart);
    finalize_kernel<<<16, 256, 0, stream>>>(rspart, pos, (float*)d_out);
}